// Round 2
// baseline (368.077 us; speedup 1.0000x reference)
//
#include <hip/hip_runtime.h>
#include <math.h>

// Problem constants (fixed by reference): x [B=16, C=64, H=256, W=256] fp32
// out [B=16, 1, H=256, W=256] fp32 = mean over C of sqrt(sobelx^2 + sobely^2 + 1e-12)
#define B_  16
#define C_  64
#define H_  256
#define W_  256

// Block tile: 16 rows x 128 cols, 256 threads (tx 0..31 -> 4 cols each, ty 0..7 -> 2 rows each).
// Each block accumulates over ALL 64 channels in fixed order -> deterministic, single store
// per output pixel, no atomics, no zero-init kernel.
__global__ __launch_bounds__(256) void sobel_kernel(const float* __restrict__ x,
                                                    float* __restrict__ out) {
    const int tx    = threadIdx.x & 31;   // col group: 4 cols
    const int ty    = threadIdx.x >> 5;   // row pair: 2 rows
    const int half  = blockIdx.x;         // 0..1  (col halves of 128)
    const int strip = blockIdx.y;         // 0..15 (16-row strips)
    const int b     = blockIdx.z;         // 0..15 batch

    const int w0 = half * 128 + tx * 4;   // first of 4 output cols
    const int r0 = strip * 16 + ty * 2;   // first of 2 output rows

    float acc0[4] = {0.f, 0.f, 0.f, 0.f};
    float acc1[4] = {0.f, 0.f, 0.f, 0.f};

    const float* xb = x + (size_t)b * C_ * H_ * W_;

    for (int c = 0; c < C_; ++c) {
        const float* plane = xb + (size_t)c * H_ * W_;

        // Separable Sobel, rolling over 4 input rows (r0-1 .. r0+2):
        //   per-row s = l + 2m + r  (smoothing),  d = r - l (difference)
        //   edge_x(row) = d(row-1) + 2 d(row) + d(row+1)
        //   edge_y(row) = s(row+1) - s(row-1)
        float4 s0 = make_float4(0,0,0,0), s1 = s0, d0 = s0, d1 = s0;

#pragma unroll
        for (int r = 0; r < 4; ++r) {
            const int gr = r0 - 1 + r;    // global input row
            float4 v; float L, R;
            if (gr >= 0 && gr < H_) {
                const float* row = plane + (size_t)gr * W_ + w0;
                v = *(const float4*)row;
                L = (w0 > 0)        ? row[-1] : 0.f;   // zero padding at W edges
                R = (w0 + 4 < W_)   ? row[4]  : 0.f;
            } else {
                v = make_float4(0,0,0,0); L = 0.f; R = 0.f;  // zero padding at H edges
            }
            float4 s2, d2;
            s2.x = L   + 2.f*v.x + v.y;
            s2.y = v.x + 2.f*v.y + v.z;
            s2.z = v.y + 2.f*v.z + v.w;
            s2.w = v.z + 2.f*v.w + R;
            d2.x = v.y - L;
            d2.y = v.z - v.x;
            d2.z = v.w - v.y;
            d2.w = R   - v.z;

            if (r >= 2) {
                float* acc = (r == 2) ? acc0 : acc1;
                float ex, ey;
                ex = d0.x + 2.f*d1.x + d2.x;  ey = s2.x - s0.x;
                acc[0] += sqrtf(ex*ex + ey*ey + 1e-12f);
                ex = d0.y + 2.f*d1.y + d2.y;  ey = s2.y - s0.y;
                acc[1] += sqrtf(ex*ex + ey*ey + 1e-12f);
                ex = d0.z + 2.f*d1.z + d2.z;  ey = s2.z - s0.z;
                acc[2] += sqrtf(ex*ex + ey*ey + 1e-12f);
                ex = d0.w + 2.f*d1.w + d2.w;  ey = s2.w - s0.w;
                acc[3] += sqrtf(ex*ex + ey*ey + 1e-12f);
            }
            s0 = s1; s1 = s2;
            d0 = d1; d1 = d2;
        }
    }

    const float scale = 1.f / (float)C_;
    float4 o0, o1;
    o0.x = acc0[0]*scale; o0.y = acc0[1]*scale; o0.z = acc0[2]*scale; o0.w = acc0[3]*scale;
    o1.x = acc1[0]*scale; o1.y = acc1[1]*scale; o1.z = acc1[2]*scale; o1.w = acc1[3]*scale;

    float* ob = out + ((size_t)b * H_ + r0) * W_ + w0;
    *(float4*)ob          = o0;
    *(float4*)(ob + W_)   = o1;
}

extern "C" void kernel_launch(void* const* d_in, const int* in_sizes, int n_in,
                              void* d_out, int out_size, void* d_ws, size_t ws_size,
                              hipStream_t stream) {
    const float* x = (const float*)d_in[0];
    float* out = (float*)d_out;

    dim3 grid(2, H_ / 16, B_);  // (2 col-halves, 16 row strips, 16 batch) = 512 blocks
    sobel_kernel<<<grid, 256, 0, stream>>>(x, out);
}

// Round 3
// 368.010 us; speedup vs baseline: 1.0002x; 1.0002x over previous
//
#include <hip/hip_runtime.h>
#include <math.h>

// x [B=16, C=64, H=256, W=256] fp32 -> out [16,1,256,256] fp32
// out = mean_c sqrt(sobelx^2 + sobely^2 + 1e-12), zero-padded 3x3
#define B_  16
#define C_  64
#define H_  256
#define W_  256
#define R_  8     // output rows per block (and per wave)
#define CPW 16    // channels per wave (4 waves x 16 = 64)

// Block: 256 threads = 4 waves. Each wave spans the full 256-col row
// (lane*4 cols) and owns R_=8 output rows for CPW=16 channels; the four
// wave partials are combined through LDS in fixed order -> deterministic,
// each output pixel written exactly once. Horizontal neighbors via __shfl
// (1 vector load per row instead of 3 loads). Vertical halo 10/8 = 1.25x.
__global__ __launch_bounds__(256) void sobel_kernel(const float* __restrict__ x,
                                                    float* __restrict__ out) {
    const int lane  = threadIdx.x & 63;
    const int wv    = threadIdx.x >> 6;   // 0..3
    const int strip = blockIdx.x;         // 0..31
    const int b     = blockIdx.y;         // 0..15
    const int w0    = lane * 4;
    const int r0    = strip * R_;

    float4 acc[R_];
#pragma unroll
    for (int r = 0; r < R_; ++r) acc[r] = make_float4(0.f, 0.f, 0.f, 0.f);

    const float* xb = x + ((size_t)b * C_ + wv * CPW) * (H_ * W_);

    for (int cc = 0; cc < CPW; ++cc) {
        const float* plane = xb + (size_t)cc * (H_ * W_);

        // Preload all 10 rows (r0-1 .. r0+8) unconditionally (clamped row
        // index keeps the address in-bounds) -> 10 dwordx4 in flight.
        float4 v[R_ + 2];
#pragma unroll
        for (int rr = 0; rr < R_ + 2; ++rr) {
            int gr  = r0 - 1 + rr;
            int grc = min(max(gr, 0), H_ - 1);
            v[rr] = *(const float4*)(plane + (size_t)grc * W_ + w0);
        }
        // Zero-padding: only the first/last halo row can be OOB.
        if (r0 == 0)        v[0]      = make_float4(0.f, 0.f, 0.f, 0.f);
        if (r0 + R_ == H_)  v[R_ + 1] = make_float4(0.f, 0.f, 0.f, 0.f);

        // Separable Sobel rolling over rows:
        //   s = l + 2m + r (smooth), d = r - l (diff)
        //   ex(row) = d(row-1) + 2 d(row) + d(row+1); ey(row) = s(row+1) - s(row-1)
        float4 s0 = make_float4(0,0,0,0), s1 = s0, d0 = s0, d1 = s0;
#pragma unroll
        for (int rr = 0; rr < R_ + 2; ++rr) {
            float4 vr = v[rr];
            float L = __shfl_up(vr.w, 1);
            float R = __shfl_down(vr.x, 1);
            if (lane == 0)  L = 0.f;   // true W edge (wave spans full width)
            if (lane == 63) R = 0.f;

            float4 s2, d2;
            s2.x = L    + 2.f*vr.x + vr.y;
            s2.y = vr.x + 2.f*vr.y + vr.z;
            s2.z = vr.y + 2.f*vr.z + vr.w;
            s2.w = vr.z + 2.f*vr.w + R;
            d2.x = vr.y - L;
            d2.y = vr.z - vr.x;
            d2.z = vr.w - vr.y;
            d2.w = R    - vr.z;

            if (rr >= 2) {
                float ex, ey;
                ex = d0.x + 2.f*d1.x + d2.x;  ey = s2.x - s0.x;
                acc[rr-2].x += sqrtf(ex*ex + ey*ey + 1e-12f);
                ex = d0.y + 2.f*d1.y + d2.y;  ey = s2.y - s0.y;
                acc[rr-2].y += sqrtf(ex*ex + ey*ey + 1e-12f);
                ex = d0.z + 2.f*d1.z + d2.z;  ey = s2.z - s0.z;
                acc[rr-2].z += sqrtf(ex*ex + ey*ey + 1e-12f);
                ex = d0.w + 2.f*d1.w + d2.w;  ey = s2.w - s0.w;
                acc[rr-2].w += sqrtf(ex*ex + ey*ey + 1e-12f);
            }
            s0 = s1; s1 = s2;
            d0 = d1; d1 = d2;
        }
    }

    // Combine the 4 wave partials in fixed order via LDS (deterministic).
    __shared__ float part[4][R_][W_];   // 32 KB
#pragma unroll
    for (int r = 0; r < R_; ++r)
        *(float4*)&part[wv][r][w0] = acc[r];
    __syncthreads();

    const float scale = 1.f / (float)C_;
    float4* out4 = (float4*)out;
    for (int i = threadIdx.x; i < R_ * (W_ / 4); i += 256) {
        const int row = i >> 6;        // 0..7
        const int c4  = i & 63;        // float4 index in row
        const float4 p0 = *(const float4*)&part[0][row][c4 * 4];
        const float4 p1 = *(const float4*)&part[1][row][c4 * 4];
        const float4 p2 = *(const float4*)&part[2][row][c4 * 4];
        const float4 p3 = *(const float4*)&part[3][row][c4 * 4];
        float4 s;
        s.x = (((p0.x + p1.x) + p2.x) + p3.x) * scale;
        s.y = (((p0.y + p1.y) + p2.y) + p3.y) * scale;
        s.z = (((p0.z + p1.z) + p2.z) + p3.z) * scale;
        s.w = (((p0.w + p1.w) + p2.w) + p3.w) * scale;
        out4[((size_t)b * H_ + r0 + row) * (W_ / 4) + c4] = s;
    }
}

extern "C" void kernel_launch(void* const* d_in, const int* in_sizes, int n_in,
                              void* d_out, int out_size, void* d_ws, size_t ws_size,
                              hipStream_t stream) {
    const float* x = (const float*)d_in[0];
    float* out = (float*)d_out;
    dim3 grid(H_ / R_, B_);   // (32, 16) = 512 blocks
    sobel_kernel<<<grid, 256, 0, stream>>>(x, out);
}